// Round 5
// baseline (677.329 us; speedup 1.0000x reference)
//
#include <hip/hip_runtime.h>

#define A_DIM 5
#define B_DIM 32768
#define S_DIM 48
#define HID   256
#define LRELU 0.01f
#define BN_EPS 1e-5f
#define LDE 264   // per-wave enc tile leading dim (bf16)

// ws float layout:
//   [0, 15360)      stats partials: 160 blocks x (48 sum + 48 sq)
//   [15360, 15840)  mean[240], rstd[240]
//   [16384, 17664)  bprime[5][256]  (b_enc - (mu*rstd) @ W_enc, per agent)
//   [17664, 19712)  sq_parts[2048]  (one per wave)
//   [20480, ...)    wswz bf16 B-fragments
#define OFF_ENC 0        // 2048 frags  (N=256, K=64 padded, k<48 masked)
#define OFF_SEL 16384
#define OFF_KEY 81920
#define OFF_C1  147456
#define OFF_C2  212992

typedef __bf16 bf16x8 __attribute__((ext_vector_type(8)));
typedef float  f32x4  __attribute__((ext_vector_type(4)));
typedef unsigned uint2v __attribute__((ext_vector_type(2)));

__device__ __forceinline__ unsigned short f2bf(float x) {
    unsigned u = __builtin_bit_cast(unsigned, x);
    unsigned r = (u + 0x7FFFu + ((u >> 16) & 1u)) >> 16;
    return (unsigned short)r;
}
__device__ __forceinline__ unsigned pk2(float lo, float hi) {
    return (unsigned)f2bf(lo) | ((unsigned)f2bf(hi) << 16);
}
__device__ __forceinline__ float bflo(unsigned u) {
    return __builtin_bit_cast(float, u << 16);
}
__device__ __forceinline__ float bfhi(unsigned u) {
    return __builtin_bit_cast(float, u & 0xffff0000u);
}
__device__ __forceinline__ f32x4 mfma16(bf16x8 a, bf16x8 b, f32x4 c) {
    return __builtin_amdgcn_mfma_f32_16x16x32_bf16(a, b, c, 0, 0, 0);
}
__device__ __forceinline__ float leaky(float v) { return v >= 0.f ? v : LRELU * v; }

// ---------------- Kernel A: BN partial sums (160 blocks x 256) ----------------
__global__ void stats1_kernel(const float* __restrict__ states, float* __restrict__ ws) {
    const int a = blockIdx.x >> 5;
    const int chunk = blockIdx.x & 31;
    const int t = threadIdx.x;
    const float* base = states + ((size_t)a * B_DIM + (size_t)chunk * 1024) * S_DIM;
    float s0 = 0.f, s1 = 0.f, s2 = 0.f, q0 = 0.f, q1 = 0.f, q2 = 0.f;
    for (int i = 0; i < 192; i += 3) {
        float x0 = base[t + (i + 0) * 256];
        float x1 = base[t + (i + 1) * 256];
        float x2 = base[t + (i + 2) * 256];
        s0 += x0; q0 += x0 * x0;
        s1 += x1; q1 += x1 * x1;
        s2 += x2; q2 += x2 * x2;
    }
    __shared__ float lsum[48], lsq[48];
    if (t < 48) { lsum[t] = 0.f; lsq[t] = 0.f; }
    __syncthreads();
    const int sA = t % 48, sB = (t + 16) % 48, sC = (t + 32) % 48;
    atomicAdd(&lsum[sA], s0); atomicAdd(&lsq[sA], q0);
    atomicAdd(&lsum[sB], s1); atomicAdd(&lsq[sB], q1);
    atomicAdd(&lsum[sC], s2); atomicAdd(&lsq[sC], q2);
    __syncthreads();
    if (t < 48) {
        ws[blockIdx.x * 96 + t] = lsum[t];
        ws[blockIdx.x * 96 + 48 + t] = lsq[t];
    }
}

// ---------------- Kernel B: finalize mean/rstd ----------------
__global__ void stats2_kernel(float* __restrict__ ws) {
    const int t = threadIdx.x;
    if (t >= 240) return;
    const int a = t / 48, s = t % 48;
    float sum = 0.f, sq = 0.f;
    for (int c = 0; c < 32; ++c) {
        sum += ws[(a * 32 + c) * 96 + s];
        sq  += ws[(a * 32 + c) * 96 + 48 + s];
    }
    const float mean = sum * (1.f / (float)B_DIM);
    const float var  = sq * (1.f / (float)B_DIM) - mean * mean;
    ws[15360 + t] = mean;
    ws[15600 + t] = rsqrtf(var + BN_EPS);
}

// ---------------- Kernel P: weights -> bf16 B-fragments + folded bias ----------------
// frag: dst[(fi*64+lane)*8 + j] = W[k][n], n = chunk*16+(lane&15), k = ks*32+(lane>>4)*8+j
__global__ void prep_kernel(const float* __restrict__ W_enc, const float* __restrict__ W_key,
                            const float* __restrict__ W_sel, const float* __restrict__ W_c1,
                            const float* __restrict__ W_c2, const float* __restrict__ b_enc,
                            const float* __restrict__ mr,
                            unsigned short* __restrict__ wswz, float* __restrict__ bprime) {
    const int gid = blockIdx.x * 256 + threadIdx.x;
    float vals[8];
    unsigned short* dst;
    if (gid < 2048) {                       // W_enc: chunks=16, KS=2, K pad 48->64
        const int lid = gid, lane = lid & 63, fi = lid >> 6;
        const int ks = fi & 1, chunk = fi >> 1;
        const int n = (chunk << 4) + (lane & 15), k0 = ks * 32 + ((lane >> 4) << 3);
#pragma unroll
        for (int j = 0; j < 8; ++j) { int k = k0 + j; vals[j] = (k < 48) ? W_enc[k * 256 + n] : 0.f; }
        dst = wswz + OFF_ENC + (size_t)lid * 8;
    } else if (gid < 10240) {               // W_sel cat
        const int lid = gid - 2048, lane = lid & 63, fi = lid >> 6;
        const int ks = fi & 7, chunk = fi >> 3;
        const int n = (chunk << 4) + (lane & 15), k0 = ks * 32 + ((lane >> 4) << 3);
        const int head = n >> 6, d = n & 63;
#pragma unroll
        for (int j = 0; j < 8; ++j) { int k = k0 + j; vals[j] = W_sel[(head * 256 + k) * 64 + d]; }
        dst = wswz + OFF_SEL + (size_t)lid * 8;
    } else if (gid < 18432) {               // W_key cat
        const int lid = gid - 10240, lane = lid & 63, fi = lid >> 6;
        const int ks = fi & 7, chunk = fi >> 3;
        const int n = (chunk << 4) + (lane & 15), k0 = ks * 32 + ((lane >> 4) << 3);
        const int head = n >> 6, d = n & 63;
#pragma unroll
        for (int j = 0; j < 8; ++j) { int k = k0 + j; vals[j] = W_key[(head * 256 + k) * 64 + d]; }
        dst = wswz + OFF_KEY + (size_t)lid * 8;
    } else if (gid < 26624) {               // W_c1
        const int lid = gid - 18432, lane = lid & 63, fi = lid >> 6;
        const int ks = fi & 7, chunk = fi >> 3;
        const int n = (chunk << 4) + (lane & 15), k0 = ks * 32 + ((lane >> 4) << 3);
#pragma unroll
        for (int j = 0; j < 8; ++j) { int k = k0 + j; vals[j] = W_c1[k * 256 + n]; }
        dst = wswz + OFF_C1 + (size_t)lid * 8;
    } else if (gid < 27136) {               // W_c2: N pad 8->16
        const int lid = gid - 26624, lane = lid & 63, ks = lid >> 6;
        const int n = lane & 15, k0 = ks * 32 + ((lane >> 4) << 3);
#pragma unroll
        for (int j = 0; j < 8; ++j) { int k = k0 + j; vals[j] = (n < 8) ? W_c2[k * 8 + n] : 0.f; }
        dst = wswz + OFF_C2 + (size_t)lid * 8;
    } else if (gid < 27136 + 1280) {        // bprime[a][n] = b_enc[n] - sum_s mu*rstd*W_enc
        const int idx = gid - 27136, a = idx >> 8, n = idx & 255;
        float acc = 0.f;
        for (int s = 0; s < 48; ++s)
            acc += mr[a * 48 + s] * mr[240 + a * 48 + s] * W_enc[s * 256 + n];
        bprime[a * 256 + n] = b_enc[n] - acc;
        return;
    } else return;
#pragma unroll
    for (int j = 0; j < 8; ++j) dst[j] = f2bf(vals[j]);
}

// ---------------- Kernel C: barrier-free main (512 blocks x 256 threads) ----------------
// Each wave owns 16 rows end-to-end; wave-private LDS tile; no inter-wave sync.
__global__ void __launch_bounds__(256, 3)
main_kernel(const float* __restrict__ states,
            const float* __restrict__ b_c1, const float* __restrict__ b_c2,
            const unsigned short* __restrict__ wswz,
            const float* __restrict__ mr, const float* __restrict__ bprime,
            float* __restrict__ out, float* __restrict__ sq_parts)
{
    __shared__ unsigned short encS[4][16 * LDE];   // per-wave 16x264 bf16
    __shared__ float biasL[1544];                  // bprime[1280] | b_c1[256] | b_c2[8]
    __shared__ float rstdL[240];

    const int t    = threadIdx.x;
    const int lane = t & 63;
    const int w    = t >> 6;
    const int l15  = lane & 15;
    const int lg   = lane >> 4;
    const int gr0  = blockIdx.x * 64 + w * 16;     // wave's first batch row
    unsigned short* encW = &encS[w][0];

    // one-time block staging (the only barrier in the kernel)
    for (int i = t; i < 1280; i += 256) biasL[i] = bprime[i];
    if (t < 256) biasL[1280 + t] = b_c1[t];
    if (t < 8)   biasL[1536 + t] = b_c2[t];
    for (int i = t; i < 240; i += 256) rstdL[i] = mr[240 + i];
    __syncthreads();

    unsigned selP[16][2];   // sel in packed bf16 (acc layout), persists across agents
    float sqacc = 0.f;

    for (int a = 0; a < A_DIM; ++a) {
        // ---- x-fragments straight from global (row = l15, k = ks*32+lg*8+j), scaled by rstd ----
        const float* xp = states + ((size_t)a * B_DIM + gr0 + l15) * S_DIM;
        bf16x8 xf0, xf1;
        {
            f32x4 x0 = __builtin_nontemporal_load((const f32x4*)(xp + lg * 8));
            f32x4 x1 = __builtin_nontemporal_load((const f32x4*)(xp + lg * 8 + 4));
            f32x4 r0 = *(const f32x4*)&rstdL[a * 48 + lg * 8];
            f32x4 r1 = *(const f32x4*)&rstdL[a * 48 + lg * 8 + 4];
            x0 *= r0; x1 *= r1;
            uint4 u; u.x = pk2(x0[0], x0[1]); u.y = pk2(x0[2], x0[3]);
            u.z = pk2(x1[0], x1[1]); u.w = pk2(x1[2], x1[3]);
            xf0 = __builtin_bit_cast(bf16x8, u);
            if (lg < 2) {
                f32x4 x2 = __builtin_nontemporal_load((const f32x4*)(xp + 32 + lg * 8));
                f32x4 x3 = __builtin_nontemporal_load((const f32x4*)(xp + 36 + lg * 8));
                f32x4 r2 = *(const f32x4*)&rstdL[a * 48 + 32 + lg * 8];
                f32x4 r3 = *(const f32x4*)&rstdL[a * 48 + 36 + lg * 8];
                x2 *= r2; x3 *= r3;
                uint4 v; v.x = pk2(x2[0], x2[1]); v.y = pk2(x2[2], x2[3]);
                v.z = pk2(x3[0], x3[1]); v.w = pk2(x3[2], x3[3]);
                xf1 = __builtin_bit_cast(bf16x8, v);
            } else {
                uint4 z = {0, 0, 0, 0};
                xf1 = __builtin_bit_cast(bf16x8, z);
            }
        }

        // ---- enc^T = mfma(W_frag, x_frag): col=l15=brow, row=h ----
        f32x4 acc[16];
#pragma unroll
        for (int ch = 0; ch < 16; ++ch) {
            bf16x8 b0 = *(const bf16x8*)(wswz + OFF_ENC + ((size_t)((ch * 2 + 0) * 64 + lane)) * 8);
            bf16x8 b1 = *(const bf16x8*)(wswz + OFF_ENC + ((size_t)((ch * 2 + 1) * 64 + lane)) * 8);
            f32x4 z = {0.f, 0.f, 0.f, 0.f};
            acc[ch] = mfma16(b0, xf0, z);
            acc[ch] = mfma16(b1, xf1, acc[ch]);
        }
        // bias + leaky + pack -> enc tile [brow][h] via b64 stores
#pragma unroll
        for (int ch = 0; ch < 16; ++ch) {
            f32x4 bb = *(const f32x4*)&biasL[a * 256 + ch * 16 + lg * 4];
            float v0 = leaky(acc[ch][0] + bb[0]), v1 = leaky(acc[ch][1] + bb[1]);
            float v2 = leaky(acc[ch][2] + bb[2]), v3 = leaky(acc[ch][3] + bb[3]);
            uint2v pv; pv.x = pk2(v0, v1); pv.y = pk2(v2, v3);
            *(uint2v*)(encW + l15 * LDE + ch * 16 + lg * 4) = pv;
        }

        if (a == 0) {
            // sel^T = mfma(Wsel_frag, enc_frag) -> packed regs
            f32x4 acc2[16] = {};
#pragma unroll
            for (int ks = 0; ks < 8; ++ks) {
                bf16x8 ef = *(const bf16x8*)(encW + l15 * LDE + ks * 32 + lg * 8);
#pragma unroll
                for (int ch = 0; ch < 16; ++ch) {
                    bf16x8 bw = *(const bf16x8*)(wswz + OFF_SEL + ((size_t)((ch * 8 + ks) * 64 + lane)) * 8);
                    acc2[ch] = mfma16(bw, ef, acc2[ch]);
                }
            }
#pragma unroll
            for (int ch = 0; ch < 16; ++ch) {
                selP[ch][0] = pk2(acc2[ch][0], acc2[ch][1]);
                selP[ch][1] = pk2(acc2[ch][2], acc2[ch][3]);
            }
            // h^T = leaky(mfma(Wc1_frag, enc_frag) + b_c1) -> overwrite enc tile
            f32x4 acc3[16] = {};
#pragma unroll
            for (int ks = 0; ks < 8; ++ks) {
                bf16x8 ef = *(const bf16x8*)(encW + l15 * LDE + ks * 32 + lg * 8);
#pragma unroll
                for (int ch = 0; ch < 16; ++ch) {
                    bf16x8 bw = *(const bf16x8*)(wswz + OFF_C1 + ((size_t)((ch * 8 + ks) * 64 + lane)) * 8);
                    acc3[ch] = mfma16(bw, ef, acc3[ch]);
                }
            }
#pragma unroll
            for (int ch = 0; ch < 16; ++ch) {
                f32x4 bb = *(const f32x4*)&biasL[1280 + ch * 16 + lg * 4];
                float v0 = leaky(acc3[ch][0] + bb[0]), v1 = leaky(acc3[ch][1] + bb[1]);
                float v2 = leaky(acc3[ch][2] + bb[2]), v3 = leaky(acc3[ch][3] + bb[3]);
                uint2v pv; pv.x = pk2(v0, v1); pv.y = pk2(v2, v3);
                *(uint2v*)(encW + l15 * LDE + ch * 16 + lg * 4) = pv;
            }
            // all_q^T = mfma(Wc2_frag, h_frag): row = n (lg*4+r, <8 valid), col = brow
            f32x4 q = {0.f, 0.f, 0.f, 0.f};
#pragma unroll
            for (int ks = 0; ks < 8; ++ks) {
                bf16x8 hf = *(const bf16x8*)(encW + l15 * LDE + ks * 32 + lg * 8);
                bf16x8 bw = *(const bf16x8*)(wswz + OFF_C2 + ((size_t)(ks * 64 + lane)) * 8);
                q = mfma16(bw, hf, q);
            }
            if (lg < 2) {
                f32x4 bb = *(const f32x4*)&biasL[1536 + lg * 4];
                f32x4 o = {q[0] + bb[0], q[1] + bb[1], q[2] + bb[2], q[3] + bb[3]};
                __builtin_nontemporal_store(o, (f32x4*)&out[(size_t)(gr0 + l15) * 8 + lg * 4]);
            }
        } else {
            // keys^T = mfma(Wkey_frag, enc_frag); logits = <sel, key> elementwise in acc layout
            f32x4 acc2[16] = {};
#pragma unroll
            for (int ks = 0; ks < 8; ++ks) {
                bf16x8 ef = *(const bf16x8*)(encW + l15 * LDE + ks * 32 + lg * 8);
#pragma unroll
                for (int ch = 0; ch < 16; ++ch) {
                    bf16x8 bw = *(const bf16x8*)(wswz + OFF_KEY + ((size_t)((ch * 8 + ks) * 64 + lane)) * 8);
                    acc2[ch] = mfma16(bw, ef, acc2[ch]);
                }
            }
#pragma unroll
            for (int k = 0; k < 4; ++k) {
                float p = 0.f;
#pragma unroll
                for (int c = 0; c < 4; ++c) {
                    const int ch = k * 4 + c;
                    p += bflo(selP[ch][0]) * acc2[ch][0] + bfhi(selP[ch][0]) * acc2[ch][1]
                       + bflo(selP[ch][1]) * acc2[ch][2] + bfhi(selP[ch][1]) * acc2[ch][3];
                }
                p += __shfl_xor(p, 16);
                p += __shfl_xor(p, 32);   // now full sum over d; replicated 4x across lg
                sqacc += p * p;
            }
        }
    }

    // wave-level reduce of sqacc -> one slot per wave (no barrier needed)
    float v = sqacc;
#pragma unroll
    for (int m = 1; m < 64; m <<= 1) v += __shfl_xor(v, m);
    if (lane == 0) sq_parts[blockIdx.x * 4 + w] = v;
}

// ---------------- Kernel D: final reg reduce ----------------
__global__ void reduce_reg_kernel(const float* __restrict__ sq_parts, float* __restrict__ out_reg) {
    __shared__ float red[256];
    const int t = threadIdx.x;
    float s = 0.f;
#pragma unroll
    for (int i = 0; i < 8; ++i) s += sq_parts[t + i * 256];
    red[t] = s;
    __syncthreads();
    for (int k = 128; k > 0; k >>= 1) {
        if (t < k) red[t] += red[t + k];
        __syncthreads();
    }
    // sum counts each (k,b,a) 4x (lg replication): scale = 0.001/(B*4agents*4)
    if (t == 0) out_reg[0] = red[0] * (0.001f / ((float)B_DIM * 16.f));
}

extern "C" void kernel_launch(void* const* d_in, const int* in_sizes, int n_in,
                              void* d_out, int out_size, void* d_ws, size_t ws_size,
                              hipStream_t stream) {
    const float* states = (const float*)d_in[0];
    const float* W_enc  = (const float*)d_in[1];
    const float* b_enc  = (const float*)d_in[2];
    const float* W_key  = (const float*)d_in[3];
    const float* W_sel  = (const float*)d_in[4];
    // d_in[5]=W_val, d_in[6]=b_val: dead (multiplied by 0.0 in reference)
    const float* W_c1   = (const float*)d_in[7];
    const float* b_c1   = (const float*)d_in[8];
    const float* W_c2   = (const float*)d_in[9];
    const float* b_c2   = (const float*)d_in[10];
    float* out = (float*)d_out;
    float* ws  = (float*)d_ws;

    float* mr       = ws + 15360;   // mean[240], rstd[240]
    float* bprime   = ws + 16384;   // 1280
    float* sq_parts = ws + 17664;   // 2048
    unsigned short* wswz = (unsigned short*)(ws + 20480);

    stats1_kernel<<<160, 256, 0, stream>>>(states, ws);
    stats2_kernel<<<1, 256, 0, stream>>>(ws);
    prep_kernel<<<111, 256, 0, stream>>>(W_enc, W_key, W_sel, W_c1, W_c2, b_enc,
                                         mr, wswz, bprime);
    main_kernel<<<512, 256, 0, stream>>>(states, b_c1, b_c2, wswz, mr, bprime,
                                         out, sq_parts);
    reduce_reg_kernel<<<1, 256, 0, stream>>>(sq_parts, out + (size_t)B_DIM * 8);
}

// Round 6
// 123.873 us; speedup vs baseline: 5.4679x; 5.4679x over previous
//
#include <hip/hip_runtime.h>

#define A_DIM 5
#define B_DIM 32768
#define S_DIM 48
#define HID   256
#define LRELU 0.01f
#define BN_EPS 1e-5f

#define LDX 72    // xn LDS leading dim (bf16 elems)
#define LDE 264   // enc LDS leading dim

// ws float layout:
//   [0, 30720)      stats partials: 320 blocks x (48 sum + 48 sq)
//   [30720, 31200)  mean[240], rstd[240]
//   [31232, 31744)  sq_parts[512]
//   float 32768+ :  bf16 swizzled weight B-fragments
#define OFF_ENC 0        // 2048 frags  (N=256, K=64 padded)
#define OFF_SEL 16384
#define OFF_KEY 81920
#define OFF_C1  147456
#define OFF_C2  212992

typedef __bf16 bf16x8 __attribute__((ext_vector_type(8)));
typedef float  f32x4  __attribute__((ext_vector_type(4)));

__device__ __forceinline__ unsigned short f2bf(float x) {
    unsigned u = __builtin_bit_cast(unsigned, x);
    unsigned r = (u + 0x7FFFu + ((u >> 16) & 1u)) >> 16;
    return (unsigned short)r;
}
__device__ __forceinline__ float bf2f(unsigned short h) {
    return __builtin_bit_cast(float, (unsigned)h << 16);
}
__device__ __forceinline__ f32x4 mfma16(bf16x8 a, bf16x8 b, f32x4 c) {
    return __builtin_amdgcn_mfma_f32_16x16x32_bf16(a, b, c, 0, 0, 0);
}

// ---------------- Kernel A: BN partial sums (320 blocks x 256) ----------------
__global__ void stats1_kernel(const float* __restrict__ states, float* __restrict__ ws) {
    const int a = blockIdx.x >> 6;
    const int chunk = blockIdx.x & 63;
    const int t = threadIdx.x;
    const float* base = states + ((size_t)a * B_DIM + (size_t)chunk * 512) * S_DIM;
    float s0 = 0.f, s1 = 0.f, s2 = 0.f, q0 = 0.f, q1 = 0.f, q2 = 0.f;
    for (int i = 0; i < 96; i += 3) {
        float x0 = base[t + (i + 0) * 256];
        float x1 = base[t + (i + 1) * 256];
        float x2 = base[t + (i + 2) * 256];
        s0 += x0; q0 += x0 * x0;
        s1 += x1; q1 += x1 * x1;
        s2 += x2; q2 += x2 * x2;
    }
    __shared__ float lsum[48], lsq[48];
    if (t < 48) { lsum[t] = 0.f; lsq[t] = 0.f; }
    __syncthreads();
    const int sA = t % 48, sB = (t + 16) % 48, sC = (t + 32) % 48;
    atomicAdd(&lsum[sA], s0); atomicAdd(&lsq[sA], q0);
    atomicAdd(&lsum[sB], s1); atomicAdd(&lsq[sB], q1);
    atomicAdd(&lsum[sC], s2); atomicAdd(&lsq[sC], q2);
    __syncthreads();
    if (t < 48) {
        ws[blockIdx.x * 96 + t] = lsum[t];
        ws[blockIdx.x * 96 + 48 + t] = lsq[t];
    }
}

// ---------------- Kernel B: finalize mean/rstd ----------------
__global__ void stats2_kernel(float* __restrict__ ws) {
    const int t = threadIdx.x;
    if (t >= 240) return;
    const int a = t / 48, s = t % 48;
    float sum = 0.f, sq = 0.f;
    for (int c = 0; c < 64; ++c) {
        sum += ws[(a * 64 + c) * 96 + s];
        sq  += ws[(a * 64 + c) * 96 + 48 + s];
    }
    const float mean = sum * (1.f / (float)B_DIM);
    const float var  = sq * (1.f / (float)B_DIM) - mean * mean;
    ws[30720 + t] = mean;
    ws[30960 + t] = rsqrtf(var + BN_EPS);
}

// ---------------- Kernel P: weights -> bf16 B-fragments ----------------
__global__ void prep_kernel(const float* __restrict__ W_enc, const float* __restrict__ W_key,
                            const float* __restrict__ W_sel, const float* __restrict__ W_c1,
                            const float* __restrict__ W_c2, unsigned short* __restrict__ wswz) {
    const int gid = blockIdx.x * 256 + threadIdx.x;
    float vals[8];
    unsigned short* dst;
    if (gid < 2048) {                       // W_enc: chunks=16, KS=2, K pad 48->64
        const int lid = gid, lane = lid & 63, fi = lid >> 6;
        const int ks = fi & 1, chunk = fi >> 1;
        const int n = (chunk << 4) + (lane & 15), k0 = ks * 32 + ((lane >> 4) << 3);
#pragma unroll
        for (int j = 0; j < 8; ++j) { int k = k0 + j; vals[j] = (k < 48) ? W_enc[k * 256 + n] : 0.f; }
        dst = wswz + OFF_ENC + (size_t)lid * 8;
    } else if (gid < 10240) {               // W_sel cat
        const int lid = gid - 2048, lane = lid & 63, fi = lid >> 6;
        const int ks = fi & 7, chunk = fi >> 3;
        const int n = (chunk << 4) + (lane & 15), k0 = ks * 32 + ((lane >> 4) << 3);
        const int head = n >> 6, d = n & 63;
#pragma unroll
        for (int j = 0; j < 8; ++j) { int k = k0 + j; vals[j] = W_sel[(head * 256 + k) * 64 + d]; }
        dst = wswz + OFF_SEL + (size_t)lid * 8;
    } else if (gid < 18432) {               // W_key cat
        const int lid = gid - 10240, lane = lid & 63, fi = lid >> 6;
        const int ks = fi & 7, chunk = fi >> 3;
        const int n = (chunk << 4) + (lane & 15), k0 = ks * 32 + ((lane >> 4) << 3);
        const int head = n >> 6, d = n & 63;
#pragma unroll
        for (int j = 0; j < 8; ++j) { int k = k0 + j; vals[j] = W_key[(head * 256 + k) * 64 + d]; }
        dst = wswz + OFF_KEY + (size_t)lid * 8;
    } else if (gid < 26624) {               // W_c1
        const int lid = gid - 18432, lane = lid & 63, fi = lid >> 6;
        const int ks = fi & 7, chunk = fi >> 3;
        const int n = (chunk << 4) + (lane & 15), k0 = ks * 32 + ((lane >> 4) << 3);
#pragma unroll
        for (int j = 0; j < 8; ++j) { int k = k0 + j; vals[j] = W_c1[k * 256 + n]; }
        dst = wswz + OFF_C1 + (size_t)lid * 8;
    } else if (gid < 27136) {               // W_c2: N pad 8->16
        const int lid = gid - 26624, lane = lid & 63, ks = lid >> 6;
        const int n = lane & 15, k0 = ks * 32 + ((lane >> 4) << 3);
#pragma unroll
        for (int j = 0; j < 8; ++j) { int k = k0 + j; vals[j] = (n < 8) ? W_c2[k * 8 + n] : 0.f; }
        dst = wswz + OFF_C2 + (size_t)lid * 8;
    } else return;
#pragma unroll
    for (int j = 0; j < 8; ++j) dst[j] = f2bf(vals[j]);
}

// K-loop, B-fragments from global with explicit depth-2 register pipeline
template<int KS>
__device__ __forceinline__ void gemm_block(const unsigned short* __restrict__ aL,
                                           const unsigned short* __restrict__ bW,
                                           int l15, int lg, int lane, int w,
                                           f32x4 acc[2][4]) {
    // fragment (c, ks) lives at bW + ((w*2+c)*KS + ks)*512 + lane*8
    const unsigned short* b0p = bW + ((size_t)((w * 2 + 0) * KS) * 64 + lane) * 8;
    const unsigned short* b1p = bW + ((size_t)((w * 2 + 1) * KS) * 64 + lane) * 8;
    bf16x8 cur0 = *(const bf16x8*)(b0p);
    bf16x8 cur1 = *(const bf16x8*)(b1p);
    bf16x8 nxt0 = *(const bf16x8*)(b0p + 512);
    bf16x8 nxt1 = *(const bf16x8*)(b1p + 512);
#pragma unroll
    for (int ks = 0; ks < KS; ++ks) {
        bf16x8 af[4];
#pragma unroll
        for (int rb = 0; rb < 4; ++rb)
            af[rb] = *(const bf16x8*)(aL + (rb * 16 + l15) * LDE + ks * 32 + lg * 8);
        const bf16x8 u0 = cur0, u1 = cur1;
        cur0 = nxt0; cur1 = nxt1;
        if (ks + 2 < KS) {
            nxt0 = *(const bf16x8*)(b0p + (size_t)(ks + 2) * 512);
            nxt1 = *(const bf16x8*)(b1p + (size_t)(ks + 2) * 512);
        }
#pragma unroll
        for (int rb = 0; rb < 4; ++rb)
            acc[0][rb] = mfma16(af[rb], u0, acc[0][rb]);
#pragma unroll
        for (int rb = 0; rb < 4; ++rb)
            acc[1][rb] = mfma16(af[rb], u1, acc[1][rb]);
    }
}

__device__ __forceinline__ void store_tile(unsigned short* __restrict__ dstL, int wn, int l15, int lg,
                                           const f32x4 acc[2][4], float bias0, float bias1, bool dolrelu) {
#pragma unroll
    for (int c = 0; c < 2; ++c) {
        const float bias = c ? bias1 : bias0;
        const int col = wn + c * 16 + l15;
#pragma unroll
        for (int rb = 0; rb < 4; ++rb)
#pragma unroll
            for (int r = 0; r < 4; ++r) {
                const int row = rb * 16 + lg * 4 + r;
                float v = acc[c][rb][r] + bias;
                if (dolrelu) v = v >= 0.f ? v : LRELU * v;
                dstL[row * LDE + col] = f2bf(v);
            }
    }
}

// ---------------- Kernel C: fused main (512 blocks x 512 threads) ----------------
__global__ void __launch_bounds__(512, 4)
main_kernel(const float* __restrict__ states,
            const float* __restrict__ b_enc, const float* __restrict__ b_c1,
            const float* __restrict__ b_c2,
            const unsigned short* __restrict__ wswz,
            const float* __restrict__ meanrstd,
            float* __restrict__ out, float* __restrict__ sq_parts)
{
    extern __shared__ char smem[];
    unsigned short* xnL  = (unsigned short*)smem;            // 64*72 bf16   @0
    unsigned short* encL = xnL + 64 * LDX;                   // 64*264 bf16  @9216
    float* pbuf = (float*)(encL + 64 * LDE);                 // 8*64 f32     @43008
    float* mrL  = pbuf + 8 * 64;                             // 480 f32
    float* redF = mrL + 480;                                 // 8 f32

    const int t    = threadIdx.x;
    const int lane = t & 63;
    const int w    = t >> 6;
    const int l15  = lane & 15;
    const int lg   = lane >> 4;
    const int b0   = blockIdx.x * 64;
    const int wn   = w * 32;

    const float benc0 = b_enc[wn + l15], benc1 = b_enc[wn + 16 + l15];
    const float bc10  = b_c1[wn + l15],  bc11  = b_c1[wn + 16 + l15];

    // hoisted W_enc B-fragments (16 VGPR, reused for all 5 agents)
    bf16x8 encB[2][2];
#pragma unroll
    for (int c = 0; c < 2; ++c)
#pragma unroll
        for (int ks = 0; ks < 2; ++ks)
            encB[c][ks] = *(const bf16x8*)(wswz + OFF_ENC +
                           ((size_t)((w * 2 + c) * 2 + ks) * 64 + lane) * 8);

    // prefetch agent 0 states (nt: don't pollute L2)
    float pf[6];
    {
        const float* sp = states + (size_t)b0 * S_DIM;
#pragma unroll
        for (int j = 0; j < 6; ++j) pf[j] = __builtin_nontemporal_load(sp + t + j * 512);
    }
    // mean/rstd -> LDS; zero xn K-pad cols 48..63
    if (t < 480) mrL[t] = meanrstd[t];
    for (int i = t; i < 64 * 16; i += 512)
        xnL[(i >> 4) * LDX + 48 + (i & 15)] = 0;
    __syncthreads();

    // write xn(0)
    {
        const float* mp = mrL, *rp = mrL + 240;
#pragma unroll
        for (int j = 0; j < 6; ++j) {
            const int i = t + j * 512, row = i / 48, s = i - row * 48;
            xnL[row * LDX + s] = f2bf((pf[j] - mp[s]) * rp[s]);
        }
    }
    __syncthreads();

    float sqacc = 0.f;

    for (int a = 0; a < A_DIM; ++a) {
        // issue prefetch for next agent
        float pn[6];
        if (a < 4) {
            const float* sp = states + ((size_t)(a + 1) * B_DIM + b0) * S_DIM;
#pragma unroll
            for (int j = 0; j < 6; ++j) pn[j] = __builtin_nontemporal_load(sp + t + j * 512);
        }

        // ---- enc = leaky(xn @ W_enc + b_enc), B from registers ----
        {
            f32x4 acc[2][4] = {};
#pragma unroll
            for (int ks = 0; ks < 2; ++ks) {
                bf16x8 af[4];
#pragma unroll
                for (int rb = 0; rb < 4; ++rb)
                    af[rb] = *(const bf16x8*)(xnL + (rb * 16 + l15) * LDX + ks * 32 + lg * 8);
#pragma unroll
                for (int c = 0; c < 2; ++c)
#pragma unroll
                    for (int rb = 0; rb < 4; ++rb)
                        acc[c][rb] = mfma16(af[rb], encB[c][ks], acc[c][rb]);
            }
            // fold previous agent's logits^2 into this phase
            if (a >= 2 && t < 256) {
                const int row = t & 63, k = t >> 6;
                const float l = pbuf[(2 * k) * 64 + row] + pbuf[(2 * k + 1) * 64 + row];
                sqacc += l * l;
            }
            store_tile(encL, wn, l15, lg, acc, benc0, benc1, true);
        }
        __syncthreads();

        if (a == 0) {
            // sel = enc @ W_sel -> LDS-free? keep R3 path: sel to pbuf-less register product later
            f32x4 acc2[2][4] = {};
            gemm_block<8>(encL, wswz + OFF_SEL, l15, lg, lane, w, acc2);
            // h = leaky(enc @ W_c1 + b_c1)
            f32x4 acc3[2][4] = {};
            gemm_block<8>(encL, wswz + OFF_C1, l15, lg, lane, w, acc3);
            // stash sel into pbuf region? No: sel persists in registers (same as R3's selacc... R3 stored to selL)
            // R3 kept selL in LDS; here sel lives in acc2 -> copy to persistent regs below.
            // write xn(1)
            {
                const float* mp = mrL + 48, *rp = mrL + 240 + 48;
#pragma unroll
                for (int j = 0; j < 6; ++j) {
                    const int i = t + j * 512, row = i / 48, s = i - row * 48;
                    xnL[row * LDX + s] = f2bf((pn[j] - mp[s]) * rp[s]);
                }
            }
            __syncthreads();
            store_tile(encL, wn, l15, lg, acc3, bc10, bc11, true);   // encL <- h
            // pack sel accumulators to bf16 pairs (16 VGPR persistent instead of 32)
#pragma unroll
            for (int c = 0; c < 2; ++c)
#pragma unroll
                for (int rb = 0; rb < 4; ++rb) {
                    unsigned lo = (unsigned)f2bf(acc2[c][rb][0]) | ((unsigned)f2bf(acc2[c][rb][1]) << 16);
                    unsigned hi = (unsigned)f2bf(acc2[c][rb][2]) | ((unsigned)f2bf(acc2[c][rb][3]) << 16);
                    pbuf[(c * 4 + rb) * 64 + lane] = __builtin_bit_cast(float, lo);
                    pbuf[(c * 4 + rb + 8) * 64 + lane] = __builtin_bit_cast(float, hi);
                }
            __syncthreads();
            // all_q = h @ W_c2 + b_c2
            if (w < 4) {
                f32x4 q = {};
#pragma unroll
                for (int ks = 0; ks < 8; ++ks) {
                    bf16x8 af = *(const bf16x8*)(encL + (w * 16 + l15) * LDE + ks * 32 + lg * 8);
                    bf16x8 bf = *(const bf16x8*)(wswz + OFF_C2 + ((size_t)(ks * 64 + lane)) * 8);
                    q = mfma16(af, bf, q);
                }
                if (l15 < 8) {
                    const float bq = b_c2[l15];
#pragma unroll
                    for (int r = 0; r < 4; ++r) {
                        const int row = w * 16 + lg * 4 + r;
                        __builtin_nontemporal_store(q[r] + bq, &out[(size_t)(b0 + row) * 8 + l15]);
                    }
                }
            }
            __syncthreads();
        } else {
            // keys = enc @ W_key (pipelined); logits = <sel, key> elementwise via LDS-held sel
            f32x4 acc2[2][4] = {};
            gemm_block<8>(encL, wswz + OFF_KEY, l15, lg, lane, w, acc2);
            float p[4][4];
#pragma unroll
            for (int rb = 0; rb < 4; ++rb)
#pragma unroll
                for (int r = 0; r < 4; ++r) p[rb][r] = 0.f;
#pragma unroll
            for (int c = 0; c < 2; ++c)
#pragma unroll
                for (int rb = 0; rb < 4; ++rb) {
                    const unsigned lo = __builtin_bit_cast(unsigned, pbuf[(c * 4 + rb) * 64 + lane]);
                    const unsigned hi = __builtin_bit_cast(unsigned, pbuf[(c * 4 + rb + 8) * 64 + lane]);
                    p[rb][0] += bf2f((unsigned short)(lo & 0xffff)) * acc2[c][rb][0];
                    p[rb][1] += bf2f((unsigned short)(lo >> 16))    * acc2[c][rb][1];
                    p[rb][2] += bf2f((unsigned short)(hi & 0xffff)) * acc2[c][rb][2];
                    p[rb][3] += bf2f((unsigned short)(hi >> 16))    * acc2[c][rb][3];
                }
#pragma unroll
            for (int m = 1; m < 16; m <<= 1)
#pragma unroll
                for (int rb = 0; rb < 4; ++rb)
#pragma unroll
                    for (int r = 0; r < 4; ++r)
                        p[rb][r] += __shfl_xor(p[rb][r], m);
            // accumulate logits^2 for THIS agent directly (l15==0 lanes hold sums)
            if (l15 == 0) {
                float la = 0.f;
#pragma unroll
                for (int rb = 0; rb < 4; ++rb)
#pragma unroll
                    for (int r = 0; r < 4; ++r) la += p[rb][r] * p[rb][r];
                sqacc += la;
            }
            // write xn(a+1)
            if (a < 4) {
                const float* mp = mrL + (a + 1) * 48, *rp = mrL + 240 + (a + 1) * 48;
#pragma unroll
                for (int j = 0; j < 6; ++j) {
                    const int i = t + j * 512, row = i / 48, s = i - row * 48;
                    xnL[row * LDX + s] = f2bf((pn[j] - mp[s]) * rp[s]);
                }
            }
            __syncthreads();
        }
    }

    // wave reduce, then tiny cross-wave reduce
    float v = sqacc;
#pragma unroll
    for (int m = 1; m < 64; m <<= 1) v += __shfl_xor(v, m);
    if (lane == 0) redF[w] = v;
    __syncthreads();
    if (t == 0) {
        float s = 0.f;
#pragma unroll
        for (int i = 0; i < 8; ++i) s += redF[i];
        sq_parts[blockIdx.x] = s;
    }
}

// ---------------- Kernel D: final reg reduce ----------------
__global__ void reduce_reg_kernel(const float* __restrict__ sq_parts, float* __restrict__ out_reg) {
    __shared__ float red[256];
    const int t = threadIdx.x;
    red[t] = sq_parts[t] + sq_parts[t + 256];
    __syncthreads();
    for (int s = 128; s > 0; s >>= 1) {
        if (t < s) red[t] += red[t + s];
        __syncthreads();
    }
    if (t == 0) out_reg[0] = red[0] * (0.001f / ((float)B_DIM * 4.f));
}

extern "C" void kernel_launch(void* const* d_in, const int* in_sizes, int n_in,
                              void* d_out, int out_size, void* d_ws, size_t ws_size,
                              hipStream_t stream) {
    const float* states = (const float*)d_in[0];
    const float* W_enc  = (const float*)d_in[1];
    const float* b_enc  = (const float*)d_in[2];
    const float* W_key  = (const float*)d_in[3];
    const float* W_sel  = (const float*)d_in[4];
    // d_in[5]=W_val, d_in[6]=b_val: dead (multiplied by 0.0 in reference)
    const float* W_c1   = (const float*)d_in[7];
    const float* b_c1   = (const float*)d_in[8];
    const float* W_c2   = (const float*)d_in[9];
    const float* b_c2   = (const float*)d_in[10];
    float* out = (float*)d_out;
    float* ws  = (float*)d_ws;

    float* meanrstd = ws + 30720;
    float* sq_parts = ws + 31232;
    unsigned short* wswz = (unsigned short*)(ws + 32768);

    stats1_kernel<<<320, 256, 0, stream>>>(states, ws);
    stats2_kernel<<<1, 256, 0, stream>>>(ws);
    prep_kernel<<<106, 256, 0, stream>>>(W_enc, W_key, W_sel, W_c1, W_c2, wswz);

    const size_t ldsz = 64 * LDX * 2 + 64 * LDE * 2 + (16 * 64 + 480 + 8) * 4; // 49184 B
    main_kernel<<<512, 512, ldsz, stream>>>(states, b_enc, b_c1, b_c2, wswz,
                                            meanrstd, out, sq_parts);
    reduce_reg_kernel<<<1, 256, 0, stream>>>(sq_parts, out + (size_t)B_DIM * 8);
}